// Round 16
// baseline (171.123 us; speedup 1.0000x reference)
//
#include <hip/hip_runtime.h>
#include <hip/hip_bf16.h>
#include <math.h>

#define Bn 2
#define Cc 64
#define Hh 384
#define Ww 384
#define HW (Hh*Ww)          // 147456
#define Tt (Bn*HW)          // 294912 tokens

using f32x4  = __attribute__((ext_vector_type(4))) float;
using bf16x8 = __attribute__((ext_vector_type(8))) short;

// ---------------- helpers ----------------

__device__ __forceinline__ unsigned short f2bf_u(float f) {
  return __builtin_bit_cast(unsigned short, __float2bfloat16(f));
}
__device__ __forceinline__ float bf2f(unsigned short u) {
  union { unsigned u; float f; } v; v.u = ((unsigned)u) << 16;
  return v.f;
}
// exact GELU via erff (proven fast: ocml polynomial, no VCC-serialized divide)
__device__ __forceinline__ float gelu_exact(float v) {
  return 0.5f * v * (1.0f + erff(v * 0.70710678118654752f));
}

// ================= K_A: 128-token (2-window) fused block, 512 threads =================
// r9-proven structure; r16: barriers B10/B11/B12 removed (intra-wave LDS deps only --
// P11->P12 sQf, P12->P14 sX, P14->store sQf are all same-wave row ownership; cross-wave
// hazards covered by B9).

__global__ __launch_bounds__(512, 4) void kA(
    const float* __restrict__ x, unsigned short* __restrict__ x1g, unsigned short* __restrict__ yg,
    const float* __restrict__ n1w, const float* __restrict__ n1b,
    const float* __restrict__ qkvw, const float* __restrict__ qkvb,
    const float* __restrict__ posb,
    const float* __restrict__ outw, const float* __restrict__ outb,
    const float* __restrict__ cpw, const float* __restrict__ cpb,
    const float* __restrict__ pw1w, const float* __restrict__ pw1b,
    const float* __restrict__ dw1w, const float* __restrict__ dw1b,
    const float* __restrict__ tokw, const float* __restrict__ tokb,
    const float* __restrict__ n2w, const float* __restrict__ n2b,
    const float* __restrict__ lpw) {
  __shared__ char sX[16384];   // 128 rows x 128B bf16 swizzled (LN1 -> ao -> LN2)
  __shared__ char sW0[8192];   // weight dbuf 0
  __shared__ char sW1[8192];   // weight dbuf 1
  __shared__ char sQ[49152];   // 3 bf16 tiles t0/t1/t2; f32 handoff tile aliases

  const int tid = threadIdx.x;
  const int lane = tid & 63, wid = tid >> 6;          // wid 0..7
  const int fr = lane & 15, kq = lane >> 4;
  const int rtok = wid * 16 + fr;                      // token row 0..127
  const int c0own = kq * 16;                           // own channel quarter
  const int iy = wid, ix = fr;
  const int blk = blockIdx.x;
  const int b = blk / 1152;
  const int rr = blk - b * 1152;
  const int wy = rr / 24, wxp = rr - (rr / 24) * 24;
  const int h0 = wy * 8, w0 = wxp * 16;
  const long ibase = (long)b * HW;

  // ---- weight prefetch: 8 f32 regs/thread ----
  float4 wr0, wr1;
  const int wrow = tid >> 3, wc0 = (tid & 7) * 8;
  auto WLOAD = [&](const float* g) {
    const float* p = g + (long)wrow * 64 + wc0;
    wr0 = *(const float4*)p; wr1 = *(const float4*)(p + 4);
  };
  auto WSTORE = [&](char* dst) {
    bf16x8 o;
    o[0]=(short)f2bf_u(wr0.x); o[1]=(short)f2bf_u(wr0.y); o[2]=(short)f2bf_u(wr0.z); o[3]=(short)f2bf_u(wr0.w);
    o[4]=(short)f2bf_u(wr1.x); o[5]=(short)f2bf_u(wr1.y); o[6]=(short)f2bf_u(wr1.z); o[7]=(short)f2bf_u(wr1.w);
    *(bf16x8*)(dst + wrow * 128 + ((2 * wc0) ^ ((wrow & 7) << 4))) = o;
  };

  // ---- P0: gather x (16 ch/thread) + LN1 via shfl; cpw -> W0 ----
  WLOAD(cpw);
  const float* xb = x + ((long)(b * 64 + c0own)) * HW + (long)(h0 + iy) * Ww + (w0 + ix);
  float vx[16]; float s0 = 0.f, s1 = 0.f;
#pragma unroll
  for (int k = 0; k < 16; ++k) {
    float v = xb[(long)k * HW];
    vx[k] = v; s0 += v; s1 += v * v;
  }
  s0 += __shfl_xor(s0, 16); s0 += __shfl_xor(s0, 32);
  s1 += __shfl_xor(s1, 16); s1 += __shfl_xor(s1, 32);
  {
    float m = s0 * (1.f / 64.f);
    float ri = rsqrtf(s1 * (1.f / 64.f) - m * m + 1e-5f);
    const int swz = (rtok & 7) << 4;
#pragma unroll
    for (int q8 = 0; q8 < 2; ++q8) {
      bf16x8 o;
#pragma unroll
      for (int j = 0; j < 8; ++j) {
        int c = c0own + q8 * 8 + j;
        o[j] = (short)f2bf_u((vx[q8 * 8 + j] - m) * ri * n1w[c] + n1b[c]);
      }
      *(bf16x8*)(sX + rtok * 128 + ((c0own * 2 + q8 * 16) ^ swz)) = o;
    }
  }
  WSTORE(sW0); WLOAD(pw1w);
  __syncthreads();                               // B1: sX + W0(cpw) ready

  // ---- GEMM machinery: 1 m-tile (16 rows) per wave ----
  f32x4 acc[4], res[4];
  auto ZERO = [&](f32x4 a[4]) {
#pragma unroll
    for (int nt = 0; nt < 4; ++nt) a[nt] = (f32x4){0.f, 0.f, 0.f, 0.f};
  };
  auto GEMM = [&](const char* A, const char* W, f32x4 a[4]) {
#pragma unroll
    for (int kh = 0; kh < 2; ++kh) {
      const int arow = wid * 16 + fr;
      bf16x8 af = *(const bf16x8*)(A + arow * 128 + ((kh * 64 + kq * 16) ^ ((arow & 7) << 4)));
#pragma unroll
      for (int nt = 0; nt < 4; ++nt) {
        const int brow = nt * 16 + fr;
        bf16x8 bv = *(const bf16x8*)(W + brow * 128 + ((kh * 64 + kq * 16) ^ ((brow & 7) << 4)));
        a[nt] = __builtin_amdgcn_mfma_f32_16x16x32_bf16(af, bv, a[nt], 0, 0, 0);
      }
    }
  };
  auto EPI = [&](char* dst, f32x4 a[4], const float* bias) {
    const int rb = wid * 16 + kq * 4;
#pragma unroll
    for (int nt = 0; nt < 4; ++nt) {
      const int col = nt * 16 + fr;
      const float bv = bias[col];
#pragma unroll
      for (int reg = 0; reg < 4; ++reg) {
        const int row = rb + reg;
        *(unsigned short*)(dst + row * 128 + ((2 * col) ^ ((row & 7) << 4))) = f2bf_u(a[nt][reg] + bv);
      }
    }
  };
  char* t0 = sQ; char* t1 = sQ + 16384; char* t2 = sQ + 32768;
  float* sQf = (float*)sQ;    // [128][67] f32 handoff (aliases t0,t1,+1.5K of t2)

  // P3: convp GEMM (sX,W0) -> t0 ; pw1 -> W1
  ZERO(acc); GEMM(sX, sW0, acc); EPI(t0, acc, cpb);
  WSTORE(sW1); WLOAD(tokw);
  __syncthreads();                               // B2
  // P4: pw1 GEMM (t0,W1) -> t1 ; tokw -> W0
  ZERO(acc); GEMM(t0, sW1, acc); EPI(t1, acc, pw1b);
  WSTORE(sW0); WLOAD(qkvw);
  __syncthreads();                               // B3
  // P5: dw1 depthwise (t1 -> t0) ; qkv0 -> W1
  {
    const int c = tid & 63, tq = tid >> 6;
    const int wl = tq >> 2, chunk = tq & 3;
    float wv0 = dw1w[c * 3], wv1 = dw1w[c * 3 + 1], wv2 = dw1w[c * 3 + 2], bia = dw1b[c];
#pragma unroll
    for (int k = 0; k < 16; ++k) {
      int s = chunk * 16 + k;
      int r0 = ((s >> 3) << 4) + wl * 8 + (s & 7);
      float v = bia + bf2f(*(const unsigned short*)(t1 + r0 * 128 + ((2 * c) ^ ((r0 & 7) << 4)))) * wv1;
      if (s > 0) {
        int rm = (((s - 1) >> 3) << 4) + wl * 8 + ((s - 1) & 7);
        v += bf2f(*(const unsigned short*)(t1 + rm * 128 + ((2 * c) ^ ((rm & 7) << 4)))) * wv0;
      }
      if (s < 63) {
        int rp = (((s + 1) >> 3) << 4) + wl * 8 + ((s + 1) & 7);
        v += bf2f(*(const unsigned short*)(t1 + rp * 128 + ((2 * c) ^ ((rp & 7) << 4)))) * wv2;
      }
      *(unsigned short*)(t0 + r0 * 128 + ((2 * c) ^ ((r0 & 7) << 4))) = f2bf_u(v);
    }
  }
  WSTORE(sW1); WLOAD(qkvw + 4096);
  __syncthreads();                               // B4
  // P6: tok GEMM (t0,W0) -> res
  ZERO(res); GEMM(t0, sW0, res);
  __syncthreads();                               // B5 (protects W0 overwrite in P7 vs P6 readers)
  // P7: qkv0 GEMM (sX,W1) -> t0 ; qkv1 -> W0
  ZERO(acc); GEMM(sX, sW1, acc); EPI(t0, acc, qkvb);
  WSTORE(sW0); WLOAD(qkvw + 8192);
  __syncthreads();                               // B6
  // P8: qkv1 GEMM (sX,W0) -> t1 ; qkv2 -> W1
  ZERO(acc); GEMM(sX, sW0, acc); EPI(t1, acc, qkvb + 64);
  WSTORE(sW1); WLOAD(outw);
  __syncthreads();                               // B7
  // P9: qkv2 GEMM (sX,W1) -> t2 ; outw -> W0
  ZERO(acc); GEMM(sX, sW1, acc); EPI(t2, acc, qkvb + 128);
  WSTORE(sW0); WLOAD(lpw);
  __syncthreads();                               // B8
  // P10: attention (t0..t2) -> ao into sX ; lpw -> W1
  {
    const int r = rtok;
    const int h = kq;                            // one head per thread
    const int s = ((r >> 4) << 3) + (r & 7);     // window-local token
    const int swz = (r & 7) << 4;
    auto LD16 = [&](int gcol, float* o) {
      const char* base = sQ + ((gcol >> 6) * 16384) + r * 128;
      int c0 = (gcol & 63) * 2;
      bf16x8 u = *(const bf16x8*)(base + (c0 ^ swz));
      bf16x8 w2_ = *(const bf16x8*)(base + ((c0 + 16) ^ swz));
#pragma unroll
      for (int j = 0; j < 8; ++j) {
        o[j] = bf2f((unsigned short)u[j]); o[8 + j] = bf2f((unsigned short)w2_[j]);
      }
    };
    float q0[16];
    LD16(48 * h, q0);
    float sc[4];
#pragma unroll
    for (int g = 0; g < 4; ++g) {
      float kk[16]; LD16(48 * g + 16, kk);
      float a = 0.f;
#pragma unroll
      for (int d = 0; d < 16; ++d) a += q0[d] * kk[d];
      sc[g] = a * 0.25f + posb[s * 16 + h * 4 + g];
    }
    float m = fmaxf(fmaxf(sc[0], sc[1]), fmaxf(sc[2], sc[3]));
    float e[4]; float tsum = 0.f;
#pragma unroll
    for (int g = 0; g < 4; ++g) { e[g] = __expf(sc[g] - m); tsum += e[g]; }
    float inv = 1.f / tsum;
    float ao[16];
#pragma unroll
    for (int d = 0; d < 16; ++d) ao[d] = 0.f;
#pragma unroll
    for (int g = 0; g < 4; ++g) {
      float vv[16]; LD16(48 * g + 32, vv);
#pragma unroll
      for (int d = 0; d < 16; ++d) ao[d] += e[g] * vv[d];
    }
    bf16x8 o1, o2;
#pragma unroll
    for (int j = 0; j < 8; ++j) { o1[j] = (short)f2bf_u(ao[j] * inv); o2[j] = (short)f2bf_u(ao[8 + j] * inv); }
    *(bf16x8*)(sX + r * 128 + ((h * 32) ^ swz)) = o1;
    *(bf16x8*)(sX + r * 128 + ((h * 32 + 16) ^ swz)) = o2;
  }
  WSTORE(sW1);
  __syncthreads();                               // B9
  // P11: out-proj GEMM (sX=ao, W0) += res ; f32 frags -> sQf
  GEMM(sX, sW0, res);
  {
    const int rb = wid * 16 + kq * 4;
#pragma unroll
    for (int nt = 0; nt < 4; ++nt) {
      const int col = nt * 16 + fr;
      const float ob = outb[col] + tokb[col];
#pragma unroll
      for (int reg = 0; reg < 4; ++reg)
        sQf[(rb + reg) * 67 + col] = res[nt][reg] + ob;
    }
  }
  // (B10 removed: sQf producer/consumer rows are same-wave)
  // P12: residual + LN2 via shfl + x1 store + normalize -> sX (single phase)
  {
    float ss0 = 0.f, ss1 = 0.f;
#pragma unroll
    for (int k = 0; k < 16; ++k) {
      float v = sQf[rtok * 67 + c0own + k] + vx[k];
      vx[k] = v; ss0 += v; ss1 += v * v;
    }
    ss0 += __shfl_xor(ss0, 16); ss0 += __shfl_xor(ss0, 32);
    ss1 += __shfl_xor(ss1, 16); ss1 += __shfl_xor(ss1, 32);
    float m = ss0 * (1.f / 64.f);
    float ri = rsqrtf(ss1 * (1.f / 64.f) - m * m + 1e-5f);
    const int swz = (rtok & 7) << 4;
    long t = ibase + (long)(h0 + iy) * Ww + (w0 + ix);
#pragma unroll
    for (int q8 = 0; q8 < 2; ++q8) {
      bf16x8 xo, no;
#pragma unroll
      for (int j = 0; j < 8; ++j) {
        int c = c0own + q8 * 8 + j;
        float v = vx[q8 * 8 + j];
        xo[j] = (short)f2bf_u(v);
        no[j] = (short)f2bf_u((v - m) * ri * n2w[c] + n2b[c]);
      }
      *(bf16x8*)((char*)x1g + t * 128 + (c0own + q8 * 8) * 2) = xo;
      *(bf16x8*)(sX + rtok * 128 + ((c0own * 2 + q8 * 16) ^ swz)) = no;
    }
  }
  // (B11 removed: sX producer/consumer rows are same-wave; W1 visibility from B9)
  // P14: LeFF-pw GEMM (sX,W1=lpw) -> sQf -> y store
  ZERO(acc); GEMM(sX, sW1, acc);
  {
    const int rb = wid * 16 + kq * 4;
#pragma unroll
    for (int nt = 0; nt < 4; ++nt) {
      const int col = nt * 16 + fr;
#pragma unroll
      for (int reg = 0; reg < 4; ++reg)
        sQf[(rb + reg) * 67 + col] = acc[nt][reg];
    }
  }
  // (B12 removed: sQf producer/consumer rows are same-wave)
  {
    long t = ibase + (long)(h0 + iy) * Ww + (w0 + ix);
#pragma unroll
    for (int q8 = 0; q8 < 2; ++q8) {
      bf16x8 o;
#pragma unroll
      for (int j = 0; j < 8; ++j)
        o[j] = (short)f2bf_u(sQf[rtok * 67 + c0own + q8 * 8 + j]);
      *(bf16x8*)((char*)yg + t * 128 + (c0own + q8 * 8) * 2) = o;
    }
  }
}

// ================= K_B v5 (r15-proven): 512-thread + register weight prefetch + dual weight LDS =================

__global__ __launch_bounds__(512, 2) void kB(
    const unsigned short* __restrict__ yg, const unsigned short* __restrict__ x1g,
    float* __restrict__ out,
    const float* __restrict__ ldw, const float* __restrict__ ldb,
    const float* __restrict__ f1w, const float* __restrict__ f1b,
    const float* __restrict__ f2w, const float* __restrict__ f2b) {
  __shared__ char sZ0[8192];
  __shared__ char sZ1[8192];
  __shared__ char U[33792];      // halo (X-XOR swizzled) -> sWa/sH0/sH1/sWb -> sO[2]
  __shared__ float wtab[640];    // [9][64] dw weights + [64] bias

  const int tid = threadIdx.x;
  const int lane = tid & 63, wid = tid >> 6;       // 0..7
  const int fr = lane & 15, kq = lane >> 4;
  const int t_own = wid >> 2;                      // tile 0/1
  const int wv = wid & 3;                          // wave within tile
  const int bid = blockIdx.x;
  const int b = bid / 1152;
  const int r2 = bid - b * 1152;
  const int hp = r2 / 6, wseg = r2 - (r2 / 6) * 6;
  const int h0 = hp * 2, w0 = wseg * 64;
  const long ibase = (long)b * HW;
  const int cbase = fr;
  const int rbase = wv * 16 + kq * 4;              // row within own tile

  // ---- weight prefetch: 8 f32 regs/thread (64x64 tile / 512 threads) ----
  float4 wr0, wr1;
  const int wrow = tid >> 3, wc0 = (tid & 7) * 8;
  auto WLOAD = [&](const float* g, int rs) {
    const float* p = g + (long)wrow * rs + wc0;
    wr0 = *(const float4*)p; wr1 = *(const float4*)(p + 4);
  };
  auto WSTORE = [&](char* dst) {
    bf16x8 o;
    o[0]=(short)f2bf_u(wr0.x); o[1]=(short)f2bf_u(wr0.y); o[2]=(short)f2bf_u(wr0.z); o[3]=(short)f2bf_u(wr0.w);
    o[4]=(short)f2bf_u(wr1.x); o[5]=(short)f2bf_u(wr1.y); o[6]=(short)f2bf_u(wr1.z); o[7]=(short)f2bf_u(wr1.w);
    *(bf16x8*)(dst + wrow * 128 + ((2 * wc0) ^ ((wrow & 7) << 4))) = o;
  };

  // preload x1 residual fragments for OWN tile only (8 regs)
  unsigned short x1r[4][4];
  {
    const long p0t = ibase + (long)(h0 + t_own) * Ww + w0;
#pragma unroll
    for (int nt = 0; nt < 4; ++nt) {
      int col = nt * 16 + cbase;
#pragma unroll
      for (int reg = 0; reg < 4; ++reg)
        x1r[nt][reg] = x1g[(p0t + rbase + reg) * 64 + col];
    }
  }

#pragma unroll
  for (int it = 0; it < 2; ++it) {
    int idx = it * 512 + tid;
    if (idx < 576) wtab[idx] = ldw[(idx & 63) * 9 + (idx >> 6)];
    else if (idx < 640) wtab[idx] = ldb[idx - 576];
  }

  // halo load: rows h0-1..h0+2, px w0-1..w0+64; X-XOR-swizzled chunks
  for (int it = 0; it < 5; ++it) {
    int idx = it * 512 + tid;
    if (idx >= 2112) break;
    int hr = idx / 528;
    int rq = idx - hr * 528;
    int px = rq >> 3, c8 = rq & 7;
    int h = h0 - 1 + hr, w = w0 - 1 + px;
    uint4 v = make_uint4(0, 0, 0, 0);
    if (h >= 0 && h < Hh && w >= 0 && w < Ww) {
      long t = ibase + (long)h * Ww + w;
      v = *(const uint4*)((const char*)yg + t * 128 + c8 * 16);
    }
    int X = hr * 66 + px;
    *(uint4*)(U + X * 128 + ((c8 * 16) ^ ((X & 7) << 4))) = v;
  }
  WLOAD(f1w, 64);                // f1w jc=0; latency hides under conv
  __syncthreads();

  // dw 3x3 conv (proven one-px-per-task form): 1024 tasks, 2 per thread
  {
    const int c8l = tid & 7;
    const int c0 = c8l * 8;
#pragma unroll
    for (int it = 0; it < 2; ++it) {
      int task = it * 512 + tid;
      int r = task >> 9;
      int px = (task >> 3) & 63;
      float a8[8];
#pragma unroll
      for (int j = 0; j < 8; ++j) a8[j] = wtab[576 + c0 + j];
#pragma unroll
      for (int dy = 0; dy < 3; ++dy)
#pragma unroll
        for (int dx = 0; dx < 3; ++dx) {
          int X = (r + dy) * 66 + px + dx;
          bf16x8 v = *(const bf16x8*)(U + X * 128 + ((c8l * 16) ^ ((X & 7) << 4)));
          const float* wk = wtab + (dy * 3 + dx) * 64 + c0;
#pragma unroll
          for (int j = 0; j < 8; ++j) a8[j] += bf2f((unsigned short)v[j]) * wk[j];
        }
      char* sZ = r ? sZ1 : sZ0;
      bf16x8 o;
#pragma unroll
      for (int j = 0; j < 8; ++j) o[j] = (short)f2bf_u(a8[j]);
      *(bf16x8*)(sZ + px * 128 + ((c8l * 16) ^ ((px & 7) << 4))) = o;
    }
  }
  __syncthreads();               // halo dead; U reusable

  char* sWa = U;
  char* sH0 = U + 8192;
  char* sH1 = U + 16384;
  char* sWb = U + 24576;
  char* sZt = t_own ? sZ1 : sZ0;
  char* sHt = t_own ? sH1 : sH0;
  f32x4 res[4];
#pragma unroll
  for (int nt = 0; nt < 4; ++nt) res[nt] = (f32x4){0.f, 0.f, 0.f, 0.f};

  WSTORE(sWa);                   // f1w_0 -> sWa
  WLOAD(f2w, 256);               // f2w_0 -> regs
  __syncthreads();               // B0: sWa ready

  for (int jc = 0; jc < 4; ++jc) {
    // fc1 on own tile (A: sZt rows, B: sWa) ; stash f2w_jc -> sWb ; issue f1w_{jc+1}
    {
      f32x4 acc[4];
#pragma unroll
      for (int nt = 0; nt < 4; ++nt) acc[nt] = (f32x4){0.f, 0.f, 0.f, 0.f};
#pragma unroll
      for (int kh = 0; kh < 2; ++kh) {
        const int arow = wv * 16 + fr;
        bf16x8 af = *(const bf16x8*)(sZt + arow * 128 + ((kh * 64 + kq * 16) ^ ((arow & 7) << 4)));
#pragma unroll
        for (int nt = 0; nt < 4; ++nt) {
          const int brow = nt * 16 + fr;
          bf16x8 bv = *(const bf16x8*)(sWa + brow * 128 + ((kh * 64 + kq * 16) ^ ((brow & 7) << 4)));
          acc[nt] = __builtin_amdgcn_mfma_f32_16x16x32_bf16(af, bv, acc[nt], 0, 0, 0);
        }
      }
      WSTORE(sWb);
      if (jc < 3) WLOAD(f1w + (jc + 1) * 4096, 64);
#pragma unroll
      for (int nt = 0; nt < 4; ++nt) {
        const int col = nt * 16 + cbase;
        const float bv = f1b[jc * 64 + col];
#pragma unroll
        for (int reg = 0; reg < 4; ++reg) {
          const int row = rbase + reg;
          *(unsigned short*)(sHt + row * 128 + ((col * 2) ^ ((row & 7) << 4))) =
              f2bf_u(gelu_exact(acc[nt][reg] + bv));
        }
      }
    }
    __syncthreads();             // B1: sHt + sWb ready
    // fc2 on own tile (A: sHt, B: sWb) -> res ; stash f1w_{jc+1} -> sWa ; issue f2w_{jc+1}
#pragma unroll
    for (int kh = 0; kh < 2; ++kh) {
      const int arow = wv * 16 + fr;
      bf16x8 af = *(const bf16x8*)(sHt + arow * 128 + ((kh * 64 + kq * 16) ^ ((arow & 7) << 4)));
#pragma unroll
      for (int nt = 0; nt < 4; ++nt) {
        const int brow = nt * 16 + fr;
        bf16x8 bv = *(const bf16x8*)(sWb + brow * 128 + ((kh * 64 + kq * 16) ^ ((brow & 7) << 4)));
        res[nt] = __builtin_amdgcn_mfma_f32_16x16x32_bf16(af, bv, res[nt], 0, 0, 0);
      }
    }
    if (jc < 3) { WSTORE(sWa); WLOAD(f2w + (jc + 1) * 64, 256); }
    __syncthreads();             // B2: next sWa ready; sHt/sWb reusable
  }

  // epilogue: both tiles into sO[2][64][65] (33280 B, fits U), then BCHW store
  float* sO = (float*)U;
#pragma unroll
  for (int nt = 0; nt < 4; ++nt) {
    const int col = nt * 16 + cbase;
    const float bv = f2b[col];
#pragma unroll
    for (int reg = 0; reg < 4; ++reg) {
      const int row = rbase + reg;
      sO[t_own * 4160 + row * 65 + col] = res[nt][reg] + bv + bf2f(x1r[nt][reg]);
    }
  }
  __syncthreads();
  {
    const int t = tid >> 8;            // 0..1
    const int tt = tid & 255;
#pragma unroll
    for (int it = 0; it < 16; ++it) {
      int c = it * 4 + (tt >> 6);
      int wo = tt & 63;
      out[(((long)(b * Cc + c)) * Hh + (h0 + t)) * Ww + w0 + wo] = sO[t * 4160 + wo * 65 + c];
    }
  }
}

// ---------------- launch ----------------

extern "C" void kernel_launch(void* const* d_in, const int* in_sizes, int n_in,
                              void* d_out, int out_size, void* d_ws, size_t ws_size,
                              hipStream_t stream) {
  const float* x    = (const float*)d_in[0];
  const float* n1w  = (const float*)d_in[1];
  const float* n1b  = (const float*)d_in[2];
  const float* qkvw = (const float*)d_in[3];
  const float* qkvb = (const float*)d_in[4];
  const float* posb = (const float*)d_in[5];
  const float* outw = (const float*)d_in[6];
  const float* outb = (const float*)d_in[7];
  const float* cpw  = (const float*)d_in[8];
  const float* cpb  = (const float*)d_in[9];
  const float* pw1w = (const float*)d_in[10];
  const float* pw1b = (const float*)d_in[11];
  const float* dw1w = (const float*)d_in[12];
  const float* dw1b = (const float*)d_in[13];
  const float* tokw = (const float*)d_in[14];
  const float* tokb = (const float*)d_in[15];
  const float* n2w  = (const float*)d_in[16];
  const float* n2b  = (const float*)d_in[17];
  const float* lpw  = (const float*)d_in[18];
  const float* ldw  = (const float*)d_in[19];
  const float* ldb  = (const float*)d_in[20];
  const float* f1w  = (const float*)d_in[21];
  const float* f1b  = (const float*)d_in[22];
  const float* f2w  = (const float*)d_in[23];
  const float* f2b  = (const float*)d_in[24];
  float* out = (float*)d_out;

  unsigned short* x1 = (unsigned short*)d_ws;        // bf16 [Tt][64]
  unsigned short* y  = x1 + (size_t)Tt * 64;         // bf16 [Tt][64]

  kA<<<dim3(2304), dim3(512), 0, stream>>>(x, x1, y, n1w, n1b, qkvw, qkvb, posb,
                                           outw, outb, cpw, cpb, pw1w, pw1b,
                                           dw1w, dw1b, tokw, tokb, n2w, n2b, lpw);
  kB<<<dim3(2304), dim3(512), 0, stream>>>(y, x1, out, ldw, ldb, f1w, f1b, f2w, f2b);
}

// Round 17
// 159.725 us; speedup vs baseline: 1.0714x; 1.0714x over previous
//
#include <hip/hip_runtime.h>
#include <hip/hip_bf16.h>
#include <math.h>

#define Bn 2
#define Cc 64
#define Hh 384
#define Ww 384
#define HW (Hh*Ww)          // 147456
#define Tt (Bn*HW)          // 294912 tokens

using f32x4  = __attribute__((ext_vector_type(4))) float;
using bf16x8 = __attribute__((ext_vector_type(8))) short;

// ---------------- helpers ----------------

__device__ __forceinline__ unsigned short f2bf_u(float f) {
  return __builtin_bit_cast(unsigned short, __float2bfloat16(f));
}
__device__ __forceinline__ float bf2f(unsigned short u) {
  union { unsigned u; float f; } v; v.u = ((unsigned)u) << 16;
  return v.f;
}
// exact GELU via erff (proven fast: ocml polynomial, no VCC-serialized divide)
__device__ __forceinline__ float gelu_exact(float v) {
  return 0.5f * v * (1.0f + erff(v * 0.70710678118654752f));
}

// ================= K_A: 128-token (2-window) fused block, 512 threads =================
// r16 structure + T5 setprio around MFMA clusters (2 blocks/CU at independent phases).

__global__ __launch_bounds__(512, 4) void kA(
    const float* __restrict__ x, unsigned short* __restrict__ x1g, unsigned short* __restrict__ yg,
    const float* __restrict__ n1w, const float* __restrict__ n1b,
    const float* __restrict__ qkvw, const float* __restrict__ qkvb,
    const float* __restrict__ posb,
    const float* __restrict__ outw, const float* __restrict__ outb,
    const float* __restrict__ cpw, const float* __restrict__ cpb,
    const float* __restrict__ pw1w, const float* __restrict__ pw1b,
    const float* __restrict__ dw1w, const float* __restrict__ dw1b,
    const float* __restrict__ tokw, const float* __restrict__ tokb,
    const float* __restrict__ n2w, const float* __restrict__ n2b,
    const float* __restrict__ lpw) {
  __shared__ char sX[16384];   // 128 rows x 128B bf16 swizzled (LN1 -> ao -> LN2)
  __shared__ char sW0[8192];   // weight dbuf 0
  __shared__ char sW1[8192];   // weight dbuf 1
  __shared__ char sQ[49152];   // 3 bf16 tiles t0/t1/t2; f32 handoff tile aliases

  const int tid = threadIdx.x;
  const int lane = tid & 63, wid = tid >> 6;          // wid 0..7
  const int fr = lane & 15, kq = lane >> 4;
  const int rtok = wid * 16 + fr;                      // token row 0..127
  const int c0own = kq * 16;                           // own channel quarter
  const int iy = wid, ix = fr;
  const int blk = blockIdx.x;
  const int b = blk / 1152;
  const int rr = blk - b * 1152;
  const int wy = rr / 24, wxp = rr - (rr / 24) * 24;
  const int h0 = wy * 8, w0 = wxp * 16;
  const long ibase = (long)b * HW;

  // ---- weight prefetch: 8 f32 regs/thread ----
  float4 wr0, wr1;
  const int wrow = tid >> 3, wc0 = (tid & 7) * 8;
  auto WLOAD = [&](const float* g) {
    const float* p = g + (long)wrow * 64 + wc0;
    wr0 = *(const float4*)p; wr1 = *(const float4*)(p + 4);
  };
  auto WSTORE = [&](char* dst) {
    bf16x8 o;
    o[0]=(short)f2bf_u(wr0.x); o[1]=(short)f2bf_u(wr0.y); o[2]=(short)f2bf_u(wr0.z); o[3]=(short)f2bf_u(wr0.w);
    o[4]=(short)f2bf_u(wr1.x); o[5]=(short)f2bf_u(wr1.y); o[6]=(short)f2bf_u(wr1.z); o[7]=(short)f2bf_u(wr1.w);
    *(bf16x8*)(dst + wrow * 128 + ((2 * wc0) ^ ((wrow & 7) << 4))) = o;
  };

  // ---- P0: gather x (16 ch/thread) + LN1 via shfl; cpw -> W0 ----
  WLOAD(cpw);
  const float* xb = x + ((long)(b * 64 + c0own)) * HW + (long)(h0 + iy) * Ww + (w0 + ix);
  float vx[16]; float s0 = 0.f, s1 = 0.f;
#pragma unroll
  for (int k = 0; k < 16; ++k) {
    float v = xb[(long)k * HW];
    vx[k] = v; s0 += v; s1 += v * v;
  }
  s0 += __shfl_xor(s0, 16); s0 += __shfl_xor(s0, 32);
  s1 += __shfl_xor(s1, 16); s1 += __shfl_xor(s1, 32);
  {
    float m = s0 * (1.f / 64.f);
    float ri = rsqrtf(s1 * (1.f / 64.f) - m * m + 1e-5f);
    const int swz = (rtok & 7) << 4;
#pragma unroll
    for (int q8 = 0; q8 < 2; ++q8) {
      bf16x8 o;
#pragma unroll
      for (int j = 0; j < 8; ++j) {
        int c = c0own + q8 * 8 + j;
        o[j] = (short)f2bf_u((vx[q8 * 8 + j] - m) * ri * n1w[c] + n1b[c]);
      }
      *(bf16x8*)(sX + rtok * 128 + ((c0own * 2 + q8 * 16) ^ swz)) = o;
    }
  }
  WSTORE(sW0); WLOAD(pw1w);
  __syncthreads();                               // B1: sX + W0(cpw) ready

  // ---- GEMM machinery: 1 m-tile (16 rows) per wave ----
  f32x4 acc[4], res[4];
  auto ZERO = [&](f32x4 a[4]) {
#pragma unroll
    for (int nt = 0; nt < 4; ++nt) a[nt] = (f32x4){0.f, 0.f, 0.f, 0.f};
  };
  auto GEMM = [&](const char* A, const char* W, f32x4 a[4]) {
    __builtin_amdgcn_s_setprio(1);
#pragma unroll
    for (int kh = 0; kh < 2; ++kh) {
      const int arow = wid * 16 + fr;
      bf16x8 af = *(const bf16x8*)(A + arow * 128 + ((kh * 64 + kq * 16) ^ ((arow & 7) << 4)));
#pragma unroll
      for (int nt = 0; nt < 4; ++nt) {
        const int brow = nt * 16 + fr;
        bf16x8 bv = *(const bf16x8*)(W + brow * 128 + ((kh * 64 + kq * 16) ^ ((brow & 7) << 4)));
        a[nt] = __builtin_amdgcn_mfma_f32_16x16x32_bf16(af, bv, a[nt], 0, 0, 0);
      }
    }
    __builtin_amdgcn_s_setprio(0);
  };
  auto EPI = [&](char* dst, f32x4 a[4], const float* bias) {
    const int rb = wid * 16 + kq * 4;
#pragma unroll
    for (int nt = 0; nt < 4; ++nt) {
      const int col = nt * 16 + fr;
      const float bv = bias[col];
#pragma unroll
      for (int reg = 0; reg < 4; ++reg) {
        const int row = rb + reg;
        *(unsigned short*)(dst + row * 128 + ((2 * col) ^ ((row & 7) << 4))) = f2bf_u(a[nt][reg] + bv);
      }
    }
  };
  char* t0 = sQ; char* t1 = sQ + 16384; char* t2 = sQ + 32768;
  float* sQf = (float*)sQ;    // [128][67] f32 handoff (aliases t0,t1,+1.5K of t2)

  // P3: convp GEMM (sX,W0) -> t0 ; pw1 -> W1
  ZERO(acc); GEMM(sX, sW0, acc); EPI(t0, acc, cpb);
  WSTORE(sW1); WLOAD(tokw);
  __syncthreads();                               // B2
  // P4: pw1 GEMM (t0,W1) -> t1 ; tokw -> W0
  ZERO(acc); GEMM(t0, sW1, acc); EPI(t1, acc, pw1b);
  WSTORE(sW0); WLOAD(qkvw);
  __syncthreads();                               // B3
  // P5: dw1 depthwise (t1 -> t0) ; qkv0 -> W1
  {
    const int c = tid & 63, tq = tid >> 6;
    const int wl = tq >> 2, chunk = tq & 3;
    float wv0 = dw1w[c * 3], wv1 = dw1w[c * 3 + 1], wv2 = dw1w[c * 3 + 2], bia = dw1b[c];
#pragma unroll
    for (int k = 0; k < 16; ++k) {
      int s = chunk * 16 + k;
      int r0 = ((s >> 3) << 4) + wl * 8 + (s & 7);
      float v = bia + bf2f(*(const unsigned short*)(t1 + r0 * 128 + ((2 * c) ^ ((r0 & 7) << 4)))) * wv1;
      if (s > 0) {
        int rm = (((s - 1) >> 3) << 4) + wl * 8 + ((s - 1) & 7);
        v += bf2f(*(const unsigned short*)(t1 + rm * 128 + ((2 * c) ^ ((rm & 7) << 4)))) * wv0;
      }
      if (s < 63) {
        int rp = (((s + 1) >> 3) << 4) + wl * 8 + ((s + 1) & 7);
        v += bf2f(*(const unsigned short*)(t1 + rp * 128 + ((2 * c) ^ ((rp & 7) << 4)))) * wv2;
      }
      *(unsigned short*)(t0 + r0 * 128 + ((2 * c) ^ ((r0 & 7) << 4))) = f2bf_u(v);
    }
  }
  WSTORE(sW1); WLOAD(qkvw + 4096);
  __syncthreads();                               // B4
  // P6: tok GEMM (t0,W0) -> res
  ZERO(res); GEMM(t0, sW0, res);
  __syncthreads();                               // B5
  // P7: qkv0 GEMM (sX,W1) -> t0 ; qkv1 -> W0
  ZERO(acc); GEMM(sX, sW1, acc); EPI(t0, acc, qkvb);
  WSTORE(sW0); WLOAD(qkvw + 8192);
  __syncthreads();                               // B6
  // P8: qkv1 GEMM (sX,W0) -> t1 ; qkv2 -> W1
  ZERO(acc); GEMM(sX, sW0, acc); EPI(t1, acc, qkvb + 64);
  WSTORE(sW1); WLOAD(outw);
  __syncthreads();                               // B7
  // P9: qkv2 GEMM (sX,W1) -> t2 ; outw -> W0
  ZERO(acc); GEMM(sX, sW1, acc); EPI(t2, acc, qkvb + 128);
  WSTORE(sW0); WLOAD(lpw);
  __syncthreads();                               // B8
  // P10: attention (t0..t2) -> ao into sX ; lpw -> W1
  {
    const int r = rtok;
    const int h = kq;                            // one head per thread
    const int s = ((r >> 4) << 3) + (r & 7);     // window-local token
    const int swz = (r & 7) << 4;
    auto LD16 = [&](int gcol, float* o) {
      const char* base = sQ + ((gcol >> 6) * 16384) + r * 128;
      int c0 = (gcol & 63) * 2;
      bf16x8 u = *(const bf16x8*)(base + (c0 ^ swz));
      bf16x8 w2_ = *(const bf16x8*)(base + ((c0 + 16) ^ swz));
#pragma unroll
      for (int j = 0; j < 8; ++j) {
        o[j] = bf2f((unsigned short)u[j]); o[8 + j] = bf2f((unsigned short)w2_[j]);
      }
    };
    float q0[16];
    LD16(48 * h, q0);
    float sc[4];
#pragma unroll
    for (int g = 0; g < 4; ++g) {
      float kk[16]; LD16(48 * g + 16, kk);
      float a = 0.f;
#pragma unroll
      for (int d = 0; d < 16; ++d) a += q0[d] * kk[d];
      sc[g] = a * 0.25f + posb[s * 16 + h * 4 + g];
    }
    float m = fmaxf(fmaxf(sc[0], sc[1]), fmaxf(sc[2], sc[3]));
    float e[4]; float tsum = 0.f;
#pragma unroll
    for (int g = 0; g < 4; ++g) { e[g] = __expf(sc[g] - m); tsum += e[g]; }
    float inv = 1.f / tsum;
    float ao[16];
#pragma unroll
    for (int d = 0; d < 16; ++d) ao[d] = 0.f;
#pragma unroll
    for (int g = 0; g < 4; ++g) {
      float vv[16]; LD16(48 * g + 32, vv);
#pragma unroll
      for (int d = 0; d < 16; ++d) ao[d] += e[g] * vv[d];
    }
    bf16x8 o1, o2;
#pragma unroll
    for (int j = 0; j < 8; ++j) { o1[j] = (short)f2bf_u(ao[j] * inv); o2[j] = (short)f2bf_u(ao[8 + j] * inv); }
    *(bf16x8*)(sX + r * 128 + ((h * 32) ^ swz)) = o1;
    *(bf16x8*)(sX + r * 128 + ((h * 32 + 16) ^ swz)) = o2;
  }
  WSTORE(sW1);
  __syncthreads();                               // B9
  // P11: out-proj GEMM (sX=ao, W0) += res ; f32 frags -> sQf
  GEMM(sX, sW0, res);
  {
    const int rb = wid * 16 + kq * 4;
#pragma unroll
    for (int nt = 0; nt < 4; ++nt) {
      const int col = nt * 16 + fr;
      const float ob = outb[col] + tokb[col];
#pragma unroll
      for (int reg = 0; reg < 4; ++reg)
        sQf[(rb + reg) * 67 + col] = res[nt][reg] + ob;
    }
  }
  // (B10 removed: sQf producer/consumer rows are same-wave)
  // P12: residual + LN2 via shfl + x1 store + normalize -> sX (single phase)
  {
    float ss0 = 0.f, ss1 = 0.f;
#pragma unroll
    for (int k = 0; k < 16; ++k) {
      float v = sQf[rtok * 67 + c0own + k] + vx[k];
      vx[k] = v; ss0 += v; ss1 += v * v;
    }
    ss0 += __shfl_xor(ss0, 16); ss0 += __shfl_xor(ss0, 32);
    ss1 += __shfl_xor(ss1, 16); ss1 += __shfl_xor(ss1, 32);
    float m = ss0 * (1.f / 64.f);
    float ri = rsqrtf(ss1 * (1.f / 64.f) - m * m + 1e-5f);
    const int swz = (rtok & 7) << 4;
    long t = ibase + (long)(h0 + iy) * Ww + (w0 + ix);
#pragma unroll
    for (int q8 = 0; q8 < 2; ++q8) {
      bf16x8 xo, no;
#pragma unroll
      for (int j = 0; j < 8; ++j) {
        int c = c0own + q8 * 8 + j;
        float v = vx[q8 * 8 + j];
        xo[j] = (short)f2bf_u(v);
        no[j] = (short)f2bf_u((v - m) * ri * n2w[c] + n2b[c]);
      }
      *(bf16x8*)((char*)x1g + t * 128 + (c0own + q8 * 8) * 2) = xo;
      *(bf16x8*)(sX + rtok * 128 + ((c0own * 2 + q8 * 16) ^ swz)) = no;
    }
  }
  // (B11 removed: sX producer/consumer rows are same-wave; W1 visibility from B9)
  // P14: LeFF-pw GEMM (sX,W1=lpw) -> sQf -> y store
  ZERO(acc); GEMM(sX, sW1, acc);
  {
    const int rb = wid * 16 + kq * 4;
#pragma unroll
    for (int nt = 0; nt < 4; ++nt) {
      const int col = nt * 16 + fr;
#pragma unroll
      for (int reg = 0; reg < 4; ++reg)
        sQf[(rb + reg) * 67 + col] = acc[nt][reg];
    }
  }
  // (B12 removed: sQf producer/consumer rows are same-wave)
  {
    long t = ibase + (long)(h0 + iy) * Ww + (w0 + ix);
#pragma unroll
    for (int q8 = 0; q8 < 2; ++q8) {
      bf16x8 o;
#pragma unroll
      for (int j = 0; j < 8; ++j)
        o[j] = (short)f2bf_u(sQf[rtok * 67 + c0own + q8 * 8 + j]);
      *(bf16x8*)((char*)yg + t * 128 + (c0own + q8 * 8) * 2) = o;
    }
  }
}

// ================= K_B v5 (r15-proven) + T5 setprio around MFMA =================

__global__ __launch_bounds__(512, 2) void kB(
    const unsigned short* __restrict__ yg, const unsigned short* __restrict__ x1g,
    float* __restrict__ out,
    const float* __restrict__ ldw, const float* __restrict__ ldb,
    const float* __restrict__ f1w, const float* __restrict__ f1b,
    const float* __restrict__ f2w, const float* __restrict__ f2b) {
  __shared__ char sZ0[8192];
  __shared__ char sZ1[8192];
  __shared__ char U[33792];      // halo (X-XOR swizzled) -> sWa/sH0/sH1/sWb -> sO[2]
  __shared__ float wtab[640];    // [9][64] dw weights + [64] bias

  const int tid = threadIdx.x;
  const int lane = tid & 63, wid = tid >> 6;       // 0..7
  const int fr = lane & 15, kq = lane >> 4;
  const int t_own = wid >> 2;                      // tile 0/1
  const int wv = wid & 3;                          // wave within tile
  const int bid = blockIdx.x;
  const int b = bid / 1152;
  const int r2 = bid - b * 1152;
  const int hp = r2 / 6, wseg = r2 - (r2 / 6) * 6;
  const int h0 = hp * 2, w0 = wseg * 64;
  const long ibase = (long)b * HW;
  const int cbase = fr;
  const int rbase = wv * 16 + kq * 4;              // row within own tile

  // ---- weight prefetch: 8 f32 regs/thread (64x64 tile / 512 threads) ----
  float4 wr0, wr1;
  const int wrow = tid >> 3, wc0 = (tid & 7) * 8;
  auto WLOAD = [&](const float* g, int rs) {
    const float* p = g + (long)wrow * rs + wc0;
    wr0 = *(const float4*)p; wr1 = *(const float4*)(p + 4);
  };
  auto WSTORE = [&](char* dst) {
    bf16x8 o;
    o[0]=(short)f2bf_u(wr0.x); o[1]=(short)f2bf_u(wr0.y); o[2]=(short)f2bf_u(wr0.z); o[3]=(short)f2bf_u(wr0.w);
    o[4]=(short)f2bf_u(wr1.x); o[5]=(short)f2bf_u(wr1.y); o[6]=(short)f2bf_u(wr1.z); o[7]=(short)f2bf_u(wr1.w);
    *(bf16x8*)(dst + wrow * 128 + ((2 * wc0) ^ ((wrow & 7) << 4))) = o;
  };

  // preload x1 residual fragments for OWN tile only (8 regs)
  unsigned short x1r[4][4];
  {
    const long p0t = ibase + (long)(h0 + t_own) * Ww + w0;
#pragma unroll
    for (int nt = 0; nt < 4; ++nt) {
      int col = nt * 16 + cbase;
#pragma unroll
      for (int reg = 0; reg < 4; ++reg)
        x1r[nt][reg] = x1g[(p0t + rbase + reg) * 64 + col];
    }
  }

#pragma unroll
  for (int it = 0; it < 2; ++it) {
    int idx = it * 512 + tid;
    if (idx < 576) wtab[idx] = ldw[(idx & 63) * 9 + (idx >> 6)];
    else if (idx < 640) wtab[idx] = ldb[idx - 576];
  }

  // halo load: rows h0-1..h0+2, px w0-1..w0+64; X-XOR-swizzled chunks
  for (int it = 0; it < 5; ++it) {
    int idx = it * 512 + tid;
    if (idx >= 2112) break;
    int hr = idx / 528;
    int rq = idx - hr * 528;
    int px = rq >> 3, c8 = rq & 7;
    int h = h0 - 1 + hr, w = w0 - 1 + px;
    uint4 v = make_uint4(0, 0, 0, 0);
    if (h >= 0 && h < Hh && w >= 0 && w < Ww) {
      long t = ibase + (long)h * Ww + w;
      v = *(const uint4*)((const char*)yg + t * 128 + c8 * 16);
    }
    int X = hr * 66 + px;
    *(uint4*)(U + X * 128 + ((c8 * 16) ^ ((X & 7) << 4))) = v;
  }
  WLOAD(f1w, 64);                // f1w jc=0; latency hides under conv
  __syncthreads();

  // dw 3x3 conv (proven one-px-per-task form): 1024 tasks, 2 per thread
  {
    const int c8l = tid & 7;
    const int c0 = c8l * 8;
#pragma unroll
    for (int it = 0; it < 2; ++it) {
      int task = it * 512 + tid;
      int r = task >> 9;
      int px = (task >> 3) & 63;
      float a8[8];
#pragma unroll
      for (int j = 0; j < 8; ++j) a8[j] = wtab[576 + c0 + j];
#pragma unroll
      for (int dy = 0; dy < 3; ++dy)
#pragma unroll
        for (int dx = 0; dx < 3; ++dx) {
          int X = (r + dy) * 66 + px + dx;
          bf16x8 v = *(const bf16x8*)(U + X * 128 + ((c8l * 16) ^ ((X & 7) << 4)));
          const float* wk = wtab + (dy * 3 + dx) * 64 + c0;
#pragma unroll
          for (int j = 0; j < 8; ++j) a8[j] += bf2f((unsigned short)v[j]) * wk[j];
        }
      char* sZ = r ? sZ1 : sZ0;
      bf16x8 o;
#pragma unroll
      for (int j = 0; j < 8; ++j) o[j] = (short)f2bf_u(a8[j]);
      *(bf16x8*)(sZ + px * 128 + ((c8l * 16) ^ ((px & 7) << 4))) = o;
    }
  }
  __syncthreads();               // halo dead; U reusable

  char* sWa = U;
  char* sH0 = U + 8192;
  char* sH1 = U + 16384;
  char* sWb = U + 24576;
  char* sZt = t_own ? sZ1 : sZ0;
  char* sHt = t_own ? sH1 : sH0;
  f32x4 res[4];
#pragma unroll
  for (int nt = 0; nt < 4; ++nt) res[nt] = (f32x4){0.f, 0.f, 0.f, 0.f};

  WSTORE(sWa);                   // f1w_0 -> sWa
  WLOAD(f2w, 256);               // f2w_0 -> regs
  __syncthreads();               // B0: sWa ready

  for (int jc = 0; jc < 4; ++jc) {
    // fc1 on own tile (A: sZt rows, B: sWa) ; stash f2w_jc -> sWb ; issue f1w_{jc+1}
    {
      f32x4 acc[4];
#pragma unroll
      for (int nt = 0; nt < 4; ++nt) acc[nt] = (f32x4){0.f, 0.f, 0.f, 0.f};
      __builtin_amdgcn_s_setprio(1);
#pragma unroll
      for (int kh = 0; kh < 2; ++kh) {
        const int arow = wv * 16 + fr;
        bf16x8 af = *(const bf16x8*)(sZt + arow * 128 + ((kh * 64 + kq * 16) ^ ((arow & 7) << 4)));
#pragma unroll
        for (int nt = 0; nt < 4; ++nt) {
          const int brow = nt * 16 + fr;
          bf16x8 bv = *(const bf16x8*)(sWa + brow * 128 + ((kh * 64 + kq * 16) ^ ((brow & 7) << 4)));
          acc[nt] = __builtin_amdgcn_mfma_f32_16x16x32_bf16(af, bv, acc[nt], 0, 0, 0);
        }
      }
      __builtin_amdgcn_s_setprio(0);
      WSTORE(sWb);
      if (jc < 3) WLOAD(f1w + (jc + 1) * 4096, 64);
#pragma unroll
      for (int nt = 0; nt < 4; ++nt) {
        const int col = nt * 16 + cbase;
        const float bv = f1b[jc * 64 + col];
#pragma unroll
        for (int reg = 0; reg < 4; ++reg) {
          const int row = rbase + reg;
          *(unsigned short*)(sHt + row * 128 + ((col * 2) ^ ((row & 7) << 4))) =
              f2bf_u(gelu_exact(acc[nt][reg] + bv));
        }
      }
    }
    __syncthreads();             // B1: sHt + sWb ready
    // fc2 on own tile (A: sHt, B: sWb) -> res ; stash f1w_{jc+1} -> sWa ; issue f2w_{jc+1}
    __builtin_amdgcn_s_setprio(1);
#pragma unroll
    for (int kh = 0; kh < 2; ++kh) {
      const int arow = wv * 16 + fr;
      bf16x8 af = *(const bf16x8*)(sHt + arow * 128 + ((kh * 64 + kq * 16) ^ ((arow & 7) << 4)));
#pragma unroll
      for (int nt = 0; nt < 4; ++nt) {
        const int brow = nt * 16 + fr;
        bf16x8 bv = *(const bf16x8*)(sWb + brow * 128 + ((kh * 64 + kq * 16) ^ ((brow & 7) << 4)));
        res[nt] = __builtin_amdgcn_mfma_f32_16x16x32_bf16(af, bv, res[nt], 0, 0, 0);
      }
    }
    __builtin_amdgcn_s_setprio(0);
    if (jc < 3) { WSTORE(sWa); WLOAD(f2w + (jc + 1) * 64, 256); }
    __syncthreads();             // B2: next sWa ready; sHt/sWb reusable
  }

  // epilogue: both tiles into sO[2][64][65] (33280 B, fits U), then BCHW store
  float* sO = (float*)U;
#pragma unroll
  for (int nt = 0; nt < 4; ++nt) {
    const int col = nt * 16 + cbase;
    const float bv = f2b[col];
#pragma unroll
    for (int reg = 0; reg < 4; ++reg) {
      const int row = rbase + reg;
      sO[t_own * 4160 + row * 65 + col] = res[nt][reg] + bv + bf2f(x1r[nt][reg]);
    }
  }
  __syncthreads();
  {
    const int t = tid >> 8;            // 0..1
    const int tt = tid & 255;
#pragma unroll
    for (int it = 0; it < 16; ++it) {
      int c = it * 4 + (tt >> 6);
      int wo = tt & 63;
      out[(((long)(b * Cc + c)) * Hh + (h0 + t)) * Ww + w0 + wo] = sO[t * 4160 + wo * 65 + c];
    }
  }
}

// ---------------- launch ----------------

extern "C" void kernel_launch(void* const* d_in, const int* in_sizes, int n_in,
                              void* d_out, int out_size, void* d_ws, size_t ws_size,
                              hipStream_t stream) {
  const float* x    = (const float*)d_in[0];
  const float* n1w  = (const float*)d_in[1];
  const float* n1b  = (const float*)d_in[2];
  const float* qkvw = (const float*)d_in[3];
  const float* qkvb = (const float*)d_in[4];
  const float* posb = (const float*)d_in[5];
  const float* outw = (const float*)d_in[6];
  const float* outb = (const float*)d_in[7];
  const float* cpw  = (const float*)d_in[8];
  const float* cpb  = (const float*)d_in[9];
  const float* pw1w = (const float*)d_in[10];
  const float* pw1b = (const float*)d_in[11];
  const float* dw1w = (const float*)d_in[12];
  const float* dw1b = (const float*)d_in[13];
  const float* tokw = (const float*)d_in[14];
  const float* tokb = (const float*)d_in[15];
  const float* n2w  = (const float*)d_in[16];
  const float* n2b  = (const float*)d_in[17];
  const float* lpw  = (const float*)d_in[18];
  const float* ldw  = (const float*)d_in[19];
  const float* ldb  = (const float*)d_in[20];
  const float* f1w  = (const float*)d_in[21];
  const float* f1b  = (const float*)d_in[22];
  const float* f2w  = (const float*)d_in[23];
  const float* f2b  = (const float*)d_in[24];
  float* out = (float*)d_out;

  unsigned short* x1 = (unsigned short*)d_ws;        // bf16 [Tt][64]
  unsigned short* y  = x1 + (size_t)Tt * 64;         // bf16 [Tt][64]

  kA<<<dim3(2304), dim3(512), 0, stream>>>(x, x1, y, n1w, n1b, qkvw, qkvb, posb,
                                           outw, outb, cpw, cpb, pw1w, pw1b,
                                           dw1w, dw1b, tokw, tokb, n2w, n2b, lpw);
  kB<<<dim3(2304), dim3(512), 0, stream>>>(y, x1, out, ldw, ldb, f1w, f1b, f2w, f2b);
}